// Round 11
// baseline (868.298 us; speedup 1.0000x reference)
//
#include <hip/hip_runtime.h>
#include <stdint.h>

#define DD 128
#define WPAD 72  // wave C-buffer row stride (u16): 144B rotates banks across
                 // rows and keeps 16B alignment for u16x8 reads.
#define EPAD 136 // gfin fused ea-tile row stride (u16): 17x8 keeps 16B align,
                 // rotates 4 banks/row -> 2-way conflict (free, m136).

typedef __bf16 bf16x8 __attribute__((ext_vector_type(8)));
typedef float f32x4 __attribute__((ext_vector_type(4)));
typedef unsigned short u16;
typedef u16 u16x8 __attribute__((ext_vector_type(8)));

// Plain cast -> single HW cvt instruction (RNE), vs ~5 VALU ops manual.
__device__ __forceinline__ u16 f2bf(float f) {
  union { __bf16 h; u16 u; } v; v.h = (__bf16)f; return v.u;
}
__device__ __forceinline__ float bf2f(u16 b) {
  union { uint32_t u; float f; } v; v.u = (uint32_t)b << 16; return v.f;
}
__device__ __forceinline__ float silu_f(float x) {
  return x / (1.0f + __expf(-x));
}
__device__ __forceinline__ uint32_t pkbf(float lo, float hi) {
  return (uint32_t)f2bf(lo) | ((uint32_t)f2bf(hi) << 16);
}

// ---- f32 A staging (streamed): issue to regs / bf16-convert into LDS ----
// LDS layout: Ab[row*128 + ((cc ^ (row&7))<<3) + (k&7)]  (cc = k>>3).
// PLAIN loads (nt loads broke gfin's resid L3 hits -- R4/R5 evidence).
struct ARegs { f32x4 v[8][2]; };

__device__ __forceinline__ void issue_A(ARegs& r, const float* __restrict__ src,
                                        int base, int M, int tid) {
#pragma unroll
  for (int i = 0; i < 8; ++i) {
    int id = tid + (i << 8);
    int row = id >> 4;
    int cc = id & 15;
    if (base + row < M) {
      const f32x4* p = (const f32x4*)(src + (size_t)(base + row) * DD + cc * 8);
      r.v[i][0] = p[0];
      r.v[i][1] = p[1];
    } else {
      r.v[i][0] = (f32x4){0.f, 0.f, 0.f, 0.f};
      r.v[i][1] = (f32x4){0.f, 0.f, 0.f, 0.f};
    }
  }
}

__device__ __forceinline__ void write_A(u16* Ab, const ARegs& r, int tid) {
#pragma unroll
  for (int i = 0; i < 8; ++i) {
    int id = tid + (i << 8);
    int row = id >> 4;
    int cc = id & 15;
    u16x8 o;
    o[0] = f2bf(r.v[i][0][0]); o[1] = f2bf(r.v[i][0][1]);
    o[2] = f2bf(r.v[i][0][2]); o[3] = f2bf(r.v[i][0][3]);
    o[4] = f2bf(r.v[i][1][0]); o[5] = f2bf(r.v[i][1][1]);
    o[6] = f2bf(r.v[i][1][2]); o[7] = f2bf(r.v[i][1][3]);
    *(u16x8*)&Ab[row * DD + ((cc ^ (row & 7)) << 3)] = o;
  }
}

// ---- B fragments preloaded to registers. Issue B loads BEFORE the store
// burst: vmcnt FIFO means waiting for B leaves stores outstanding
// (R4/R5: effective BW 1.88 -> 2.5 TB/s).
struct BRegs { bf16x8 b[4][4]; };  // [kk][n]

__device__ __forceinline__ void load_B(BRegs& br, const u16* __restrict__ wt,
                                       int lane, int wc) {
  int g = lane >> 4, r15 = lane & 15;
  const u16* wbase = wt + (size_t)(wc * 64 + r15) * DD;
#pragma unroll
  for (int kk = 0; kk < 4; ++kk) {
    int ko = ((kk << 2) | g) << 3;
#pragma unroll
    for (int n = 0; n < 4; ++n)
      br.b[kk][n] = *(const bf16x8*)&wbase[n * 16 * DD + ko];
  }
}

// ---- MFMA stage from LDS A + register B. Same lane->k bijection on A and B
// so any hw k-permutation cancels. Each wave reads only its own 64 A-rows.
__device__ __forceinline__ void mma_stage(const u16* Ab, const BRegs& br,
                                          f32x4 acc[4][4], int lane, int wr) {
  int g = lane >> 4, r15 = lane & 15, s = r15 & 7;
#pragma unroll
  for (int kk = 0; kk < 4; ++kk) {
    bf16x8 af[4];
#pragma unroll
    for (int m = 0; m < 4; ++m) {
      int rr = wr * 64 + m * 16 + r15;
      af[m] = *(const bf16x8*)&Ab[rr * DD + ((((kk << 2) | g) ^ s) << 3)];
    }
#pragma unroll
    for (int m = 0; m < 4; ++m)
#pragma unroll
      for (int n = 0; n < 4; ++n)
        acc[m][n] = __builtin_amdgcn_mfma_f32_16x16x32_bf16(af[m], br.b[kk][n], acc[m][n], 0, 0, 0);
  }
}

// acc init with per-column bias folded in (C-in of first MFMA).
__device__ __forceinline__ void init_acc(f32x4 a[4][4], const float* __restrict__ bias,
                                         int lane, int wc) {
  int l15 = lane & 15;
#pragma unroll
  for (int n = 0; n < 4; ++n) {
    float b = bias ? bias[wc * 64 + n * 16 + l15] : 0.f;
    f32x4 v = {b, b, b, b};
#pragma unroll
    for (int m = 0; m < 4; ++m) a[m][n] = v;
  }
}

// C/D: col=lane&15, row=(lane>>4)*4+reg. shfl-pair -> u32 per 2 cols, into
// this WAVE'S PRIVATE [64][WPAD] u16 staging buffer. Same-wave write->read
// needs only in-wave lgkmcnt ordering -> no block barrier (R9).
__device__ __forceinline__ void store_lds_wave(const f32x4 acc[4][4], u16* wb,
                                               int lane) {
  int l15 = lane & 15;
  bool oddl = lane & 1;
#pragma unroll
  for (int m = 0; m < 4; ++m) {
    int rb = m * 16 + ((lane >> 4) << 2);
#pragma unroll
    for (int j = 0; j < 4; ++j) {
      int row = rb + j;
#pragma unroll
      for (int n0 = 0; n0 < 4; n0 += 2) {
        int c0 = n0 * 16 + l15;
        float v0 = acc[m][n0][j];
        float v1 = acc[m][n0 + 1][j];
        float t0 = __shfl_xor(v0, 1);
        float t1 = __shfl_xor(v1, 1);
        uint32_t pk = oddl ? pkbf(t1, v1) : pkbf(v0, t0);
        int col2 = oddl ? (c0 + 15) : c0;
        *(uint32_t*)&wb[row * WPAD + col2] = pk;
      }
    }
  }
}

// Copy-out: wave buffer -> global, u16x8 (16B) per lane; 8 lanes cover one
// 128B row-segment (this wave's col-half), 8 rows per pass. The two wc-halves
// of each output row merge to full lines in L2. (R8: 330->271us vs 4B stores.)
__device__ __forceinline__ void copy_out_wave(const u16* wb, u16* __restrict__ out,
                                              size_t rs, int co, int base, int M,
                                              int lane, int wr, int wc,
                                              const int* sPerm) {
  int lr8 = lane >> 3;
  int lc = (lane & 7) * 8;
#pragma unroll
  for (int p = 0; p < 8; ++p) {
    int lrow = p * 8 + lr8;
    int row = wr * 64 + lrow;
    if (base + row < M) {
      int orow = sPerm ? sPerm[row] : (base + row);
      u16x8 v = *(const u16x8*)&wb[lrow * WPAD + lc];
      *(u16x8*)&out[(size_t)orow * rs + co + wc * 64 + lc] = v;
    }
  }
}

// ---- proj bodies (one 128-row tile per block, 64x64 wave tile) ----
__device__ __forceinline__ void proj_four_body(
    int M, int base, const float* __restrict__ src, const u16* __restrict__ wt,
    const float* __restrict__ bF, u16* __restrict__ o_sg,
    u16* __restrict__ o_dgdu, u16* __restrict__ o_su, u16* Ab, u16* Wb) {
  int tid = threadIdx.x, lane = tid & 63, wid = tid >> 6;
  int wr = wid >> 1, wc = wid & 1;
  BRegs b0, b1;
  {
    ARegs ar;
    issue_A(ar, src, base, M, tid);        // HBM loads first (longest pole)
    load_B(b0, wt + 0 * 16384, lane, wc);  // L2 loads behind them
    write_A(Ab, ar, tid);                  // waits A only (B newer in FIFO)
  }
  __syncthreads();  // the ONLY block barrier
  u16* wb = Wb + wid * (64 * WPAD);
  f32x4 acc[4][4];
  init_acc(acc, bF, lane, wc);
  mma_stage(Ab, b0, acc, lane, wr);                        // sg
  load_B(b1, wt + 1 * 16384, lane, wc);  // next B before store traffic
  store_lds_wave(acc, wb, lane);
  copy_out_wave(wb, o_sg, DD, 0, base, M, lane, wr, wc, nullptr);
  init_acc(acc, nullptr, lane, wc);
  mma_stage(Ab, b1, acc, lane, wr);                        // dg (bias in sg)
  load_B(b0, wt + 3 * 16384, lane, wc);
  store_lds_wave(acc, wb, lane);
  copy_out_wave(wb, o_dgdu, 2 * DD, 0, base, M, lane, wr, wc, nullptr);
  init_acc(acc, bF + 128, lane, wc);
  mma_stage(Ab, b0, acc, lane, wr);                        // du + bdu
  load_B(b1, wt + 4 * 16384, lane, wc);
  store_lds_wave(acc, wb, lane);
  copy_out_wave(wb, o_dgdu, 2 * DD, DD, base, M, lane, wr, wc, nullptr);
  init_acc(acc, bF + 256, lane, wc);
  mma_stage(Ab, b1, acc, lane, wr);                        // su + bsu
  store_lds_wave(acc, wb, lane);
  copy_out_wave(wb, o_su, DD, 0, base, M, lane, wr, wc, nullptr);
}

__device__ __forceinline__ void proj_one_body(
    int M, int base, const float* __restrict__ src, const u16* __restrict__ wt,
    const int* __restrict__ perm, u16* __restrict__ o,
    u16* Ab, u16* Wb, int* sPerm) {
  int tid = threadIdx.x, lane = tid & 63, wid = tid >> 6;
  int wr = wid >> 1, wc = wid & 1;
  BRegs b0;
  {
    ARegs ar;
    issue_A(ar, src, base, M, tid);
    if (perm && tid < 128)
      sPerm[tid] = (base + tid < M) ? perm[base + tid] : 0;
    load_B(b0, wt, lane, wc);
    write_A(Ab, ar, tid);
  }
  __syncthreads();
  u16* wb = Wb + wid * (64 * WPAD);
  f32x4 acc[4][4];
  init_acc(acc, nullptr, lane, wc);
  mma_stage(Ab, b0, acc, lane, wr);
  store_lds_wave(acc, wb, lane);
  copy_out_wave(wb, o, DD, 0, base, M, lane, wr, wc, perm ? sPerm : nullptr);
}

// ========== mega-launch: the 3 dependency-free projections in ONE grid =====
// (R10: 833->809us; types in contiguous grid ranges keep the tight L3 window.)
__global__ void __launch_bounds__(256, 2) proj_mega(
    int gE, int gLG,
    int E, const float* __restrict__ ex, const u16* __restrict__ wtE,
    const float* __restrict__ bFE,
    u16* __restrict__ sgE, u16* __restrict__ dgduE, u16* __restrict__ suE,
    int ELG, const float* __restrict__ lga, const u16* __restrict__ wtLG,
    const int* __restrict__ permE, u16* __restrict__ egp,
    int N, const float* __restrict__ x, const u16* __restrict__ wtN,
    const float* __restrict__ bFN,
    u16* __restrict__ sgN, u16* __restrict__ dgduN, u16* __restrict__ suN) {
  __shared__ u16 Ab[128 * DD];          // 32 KB  A tile
  __shared__ u16 Wb[4 * 64 * WPAD];     // 4 x 9 KB wave-private C staging
  __shared__ int sPerm[128];
  int b = blockIdx.x;
  if (b < gE)
    proj_four_body(E, b * 128, ex, wtE, bFE, sgE, dgduE, suE, Ab, Wb);
  else if (b < gE + gLG)
    proj_one_body(ELG, (b - gE) * 128, lga, wtLG, permE, egp, Ab, Wb, sPerm);
  else
    proj_four_body(N, (b - gE - gLG) * 128, x, wtN, bFN, sgN, dgduN, suN, Ab, Wb);
}

// Standalone single-stage projection (fallback path only: layer-2 egp).
__global__ void __launch_bounds__(256, 2) proj_single(
    int M, const float* __restrict__ src, const u16* __restrict__ wt,
    const int* __restrict__ perm, u16* __restrict__ o) {
  __shared__ u16 Ab[128 * DD];
  __shared__ u16 Wb[4 * 64 * WPAD];
  __shared__ int sPerm[128];
  proj_one_body(M, blockIdx.x * 128, src, wt, perm, o, Ab, Wb, sPerm);
}

// ================= CSR build =================
__global__ void __launch_bounds__(256) hist_kernel(const int* __restrict__ dst,
                                                   int Me, int* __restrict__ cnt) {
  int i = blockIdx.x * blockDim.x + threadIdx.x;
  if (i < Me) atomicAdd(&cnt[dst[i]], 1);
}

__global__ void __launch_bounds__(256) scan1_kernel(const int* __restrict__ cnt, int M,
                                                    int* __restrict__ out,
                                                    int* __restrict__ bsum) {
  __shared__ int sh[256];
  int t = threadIdx.x;
  int i0 = blockIdx.x * 1024 + t * 4;
  int v[4];
#pragma unroll
  for (int k = 0; k < 4; ++k) v[k] = (i0 + k < M) ? cnt[i0 + k] : 0;
  int s = v[0] + v[1] + v[2] + v[3];
  sh[t] = s;
  __syncthreads();
#pragma unroll
  for (int off = 1; off < 256; off <<= 1) {
    int x = (t >= off) ? sh[t - off] : 0;
    __syncthreads();
    sh[t] += x;
    __syncthreads();
  }
  int run = sh[t] - s;  // exclusive
  if (t == 255) bsum[blockIdx.x] = sh[255];
#pragma unroll
  for (int k = 0; k < 4; ++k) {
    if (i0 + k < M) out[i0 + k] = run;
    run += v[k];
  }
}

__global__ void __launch_bounds__(256) scan2_kernel(int* __restrict__ bsum, int NB) {
  __shared__ int sh[512];
  int t = threadIdx.x;
  for (int i = t; i < 512; i += 256) sh[i] = (i < NB) ? bsum[i] : 0;
  __syncthreads();
  for (int off = 1; off < 512; off <<= 1) {
    int tmp[2];
#pragma unroll
    for (int q = 0; q < 2; ++q) {
      int i = t + q * 256;
      tmp[q] = (i >= off) ? sh[i - off] : 0;
    }
    __syncthreads();
#pragma unroll
    for (int q = 0; q < 2; ++q) sh[t + q * 256] += tmp[q];
    __syncthreads();
  }
  for (int i = t; i < NB; i += 256) bsum[i] = (i == 0) ? 0 : sh[i - 1];
}

__global__ void __launch_bounds__(256) scan3_kernel(int* __restrict__ rowptr,
                                                    const int* __restrict__ bscan,
                                                    int M, int Medges,
                                                    int* __restrict__ head) {
  int i = blockIdx.x * blockDim.x + threadIdx.x;
  if (i < M) {
    int v = rowptr[i] + bscan[i >> 10];
    rowptr[i] = v;
    head[i] = v;
  }
  if (i == 0) rowptr[M] = Medges;
}

// Counting-sort: slot s gets the edge's src; pos[e] = s records the inverse
// permutation so proj can write egp directly in gather order.
__global__ void __launch_bounds__(256) eid_kernel(const int* __restrict__ src,
                                                  const int* __restrict__ dst, int Me,
                                                  int* __restrict__ head,
                                                  int* __restrict__ srcs,
                                                  int* __restrict__ pos) {
  int i = blockIdx.x * blockDim.x + threadIdx.x;
  if (i < Me) {
    int s = atomicAdd(&head[dst[i]], 1);
    srcs[s] = src[i];
    pos[i] = s;
  }
}

// ================= misc prep =================
// W (k-major [128][128] f32) -> wt[n*128+k] bf16.
__global__ void prep_weights(const float* __restrict__ w0, const float* __restrict__ w1,
                             const float* __restrict__ w2, const float* __restrict__ w3,
                             const float* __restrict__ w4, const float* __restrict__ w5,
                             const float* __restrict__ w6, const float* __restrict__ w7,
                             const float* __restrict__ w8, const float* __restrict__ w9,
                             u16* __restrict__ wt) {
  const float* W;
  switch (blockIdx.x) {
    case 0: W = w0; break; case 1: W = w1; break; case 2: W = w2; break;
    case 3: W = w3; break; case 4: W = w4; break; case 5: W = w5; break;
    case 6: W = w6; break; case 7: W = w7; break; case 8: W = w8; break;
    default: W = w9; break;
  }
  u16* dst = wt + blockIdx.x * 16384;
  for (int o = threadIdx.x; o < 16384; o += 256) {
    int n = o >> 7, k = o & 127;
    dst[o] = f2bf(W[k * DD + n]);
  }
}

// Folded bias table: [0..2]*128 = eu {sg+dg+eg, du, su}; [3..5]*128 = nu same.
__global__ void fold_bias(const float* __restrict__ e_sg, const float* __restrict__ e_dg,
                          const float* __restrict__ e_eg, const float* __restrict__ e_du,
                          const float* __restrict__ e_su,
                          const float* __restrict__ n_sg, const float* __restrict__ n_dg,
                          const float* __restrict__ n_eg, const float* __restrict__ n_du,
                          const float* __restrict__ n_su, float* __restrict__ out) {
  int i = threadIdx.x;
  if (i < 128) {
    out[i]        = e_sg[i] + e_dg[i] + e_eg[i];
    out[128 + i]  = e_du[i];
    out[256 + i]  = e_su[i];
    out[384 + i]  = n_sg[i] + n_dg[i] + n_eg[i];
    out[512 + i]  = n_du[i];
    out[640 + i]  = n_su[i];
  }
}

// ============ gather-finalize: 16 lanes/row, 8 cols/lane, 16 rows/block =====
// per row r: for s in [rptr[r],rptr[r+1]):
//   sv=srcs[s]
//   gate = silu(sg'[r] + dg[sv] + egp[s]); ax += gate * du'[sv]
// egp is pre-permuted (written at pos[e]) -> sequential reads here.
// vx = su'[r] + ax; LN; silu; + resid(f32); write f32 out.
// FUSE (layer 1 only): the finished 16 ea rows are exactly an MFMA A-tile ->
// project them against W_nu_eg in-block (bf16 LDS tile + 8 MFMAs/wave) and
// scatter to egp2[pos_n[r]] -- kills proj_single's 256MB ea re-read + launch.
template <bool FUSE>
__global__ void __launch_bounds__(256) gfin_kernel(
    int M, const int* __restrict__ rptr,
    const int* __restrict__ srcs,
    const u16* __restrict__ sg_t, const u16* __restrict__ dgdu_t,
    const u16* __restrict__ su_t, const u16* __restrict__ egp,
    const float* __restrict__ gamma, const float* __restrict__ beta,
    const float* __restrict__ resid, float* __restrict__ out,
    const u16* __restrict__ wtP, const int* __restrict__ posP,
    u16* __restrict__ egp2) {
  __shared__ u16 eaS[FUSE ? 16 * EPAD : 1];
  __shared__ int sPos[FUSE ? 16 : 1];
  int tid = threadIdx.x;
  int rl = tid >> 4;
  int l16 = tid & 15;
  int r = blockIdx.x * 16 + rl;
  int c = l16 * 8;
  bool act = (r < M);
  if (!FUSE && !act) return;
  if (FUSE && tid < 16)
    sPos[tid] = (blockIdx.x * 16 + tid < M) ? posP[blockIdx.x * 16 + tid] : -1;

  float o[8];
  if (act) {
    u16x8 sgp = *(const u16x8*)&sg_t[(size_t)r * DD + c];
    float sg[8], ax[8];
#pragma unroll
    for (int k = 0; k < 8; ++k) { sg[k] = bf2f(sgp[k]); ax[k] = 0.f; }

    int segb = rptr[r], sege = rptr[r + 1];
    for (int s = segb; s < sege; ++s) {
      int sv = srcs[s];
      u16x8 gp = *(const u16x8*)&egp[(size_t)s * DD + c];
      u16x8 dgp = *(const u16x8*)&dgdu_t[(size_t)sv * (2 * DD) + c];
      u16x8 dup = *(const u16x8*)&dgdu_t[(size_t)sv * (2 * DD) + DD + c];
#pragma unroll
      for (int k = 0; k < 8; ++k) {
        float g = silu_f(sg[k] + bf2f(dgp[k]) + bf2f(gp[k]));
        ax[k] += g * bf2f(dup[k]);
      }
    }

    u16x8 sup = *(const u16x8*)&su_t[(size_t)r * DD + c];
    float v[8];
    float sum = 0.f;
#pragma unroll
    for (int k = 0; k < 8; ++k) { v[k] = bf2f(sup[k]) + ax[k]; sum += v[k]; }
#pragma unroll
    for (int off = 1; off <= 8; off <<= 1) sum += __shfl_xor(sum, off);
    float mean = sum * (1.0f / 128.0f);
    float sq = 0.f;
#pragma unroll
    for (int k = 0; k < 8; ++k) { v[k] -= mean; sq += v[k] * v[k]; }
#pragma unroll
    for (int off = 1; off <= 8; off <<= 1) sq += __shfl_xor(sq, off);
    float rs = rsqrtf(sq * (1.0f / 128.0f) + 1e-5f);

    float4 gm0 = *(const float4*)&gamma[c];
    float4 gm1 = *(const float4*)&gamma[c + 4];
    float4 bt0 = *(const float4*)&beta[c];
    float4 bt1 = *(const float4*)&beta[c + 4];
    float4 rr0 = *(const float4*)&resid[(size_t)r * DD + c];
    float4 rr1 = *(const float4*)&resid[(size_t)r * DD + c + 4];
    float gmv[8] = {gm0.x, gm0.y, gm0.z, gm0.w, gm1.x, gm1.y, gm1.z, gm1.w};
    float btv[8] = {bt0.x, bt0.y, bt0.z, bt0.w, bt1.x, bt1.y, bt1.z, bt1.w};
    float rrv[8] = {rr0.x, rr0.y, rr0.z, rr0.w, rr1.x, rr1.y, rr1.z, rr1.w};
#pragma unroll
    for (int k = 0; k < 8; ++k)
      o[k] = silu_f(v[k] * rs * gmv[k] + btv[k]) + rrv[k];
    float4 o0 = {o[0], o[1], o[2], o[3]};
    float4 o1 = {o[4], o[5], o[6], o[7]};
    *(float4*)&out[(size_t)r * DD + c] = o0;
    *(float4*)&out[(size_t)r * DD + c + 4] = o1;
  }
  if (!FUSE) return;

  // ---- fused layer-2 egp projection: egp2[pos[r]] = bf16(ea[r]) @ W ----
  {
    u16x8 e8;
#pragma unroll
    for (int k = 0; k < 8; ++k) e8[k] = act ? f2bf(o[k]) : (u16)0;
    *(u16x8*)&eaS[rl * EPAD + c] = e8;
    __syncthreads();

    int lane = tid & 63, w = tid >> 6;
    int g = lane >> 4, r15 = lane & 15;
    f32x4 acc[2];
    acc[0] = (f32x4){0.f, 0.f, 0.f, 0.f};
    acc[1] = acc[0];
#pragma unroll
    for (int kk = 0; kk < 4; ++kk) {
      int ko = ((kk << 2) | g) << 3;  // same k-chunk bijection on A and B
      bf16x8 af = *(const bf16x8*)&eaS[r15 * EPAD + ko];
#pragma unroll
      for (int n = 0; n < 2; ++n) {
        bf16x8 bf = *(const bf16x8*)&wtP[(size_t)(w * 32 + n * 16 + r15) * DD + ko];
        acc[n] = __builtin_amdgcn_mfma_f32_16x16x32_bf16(af, bf, acc[n], 0, 0, 0);
      }
    }
    // C/D: col=lane&15, row=(lane>>4)*4+j; shfl-pair -> u32 per 2 cols.
    bool oddl = lane & 1;
    int c0 = w * 32 + r15;
#pragma unroll
    for (int j = 0; j < 4; ++j) {
      int row = ((lane >> 4) << 2) + j;
      int porow = sPos[row];
      float v0 = acc[0][j], v1 = acc[1][j];
      float t0 = __shfl_xor(v0, 1);
      float t1 = __shfl_xor(v1, 1);
      uint32_t pk = oddl ? pkbf(t1, v1) : pkbf(v0, t0);
      int col2 = oddl ? (c0 + 15) : c0;
      if (porow >= 0) *(uint32_t*)&egp2[(size_t)porow * DD + col2] = pk;
    }
  }
}

extern "C" void kernel_launch(void* const* d_in, const int* in_sizes, int n_in,
                              void* d_out, int out_size, void* d_ws, size_t ws_size,
                              hipStream_t stream) {
  const float* x   = (const float*)d_in[0];
  const float* ex  = (const float*)d_in[1];
  const float* lga = (const float*)d_in[2];
  const int* gei   = (const int*)d_in[3];
  const int* lgei  = (const int*)d_in[4];
  int N   = in_sizes[0] / DD;
  int E   = in_sizes[3] / 2;
  int ELG = in_sizes[4] / 2;

  char* p = (char*)d_ws;
  size_t off = 0;
  auto alloc = [&](size_t bytes) { char* q = p + off; off += (bytes + 255) & ~255ull; return q; };

  u16* wt     = (u16*)alloc((size_t)10 * 16384 * 2);
  float* biasF = (float*)alloc(768 * 4);
  u16* sgE    = (u16*)alloc((size_t)E * DD * 2);        // 128 MB
  u16* dgduE  = (u16*)alloc((size_t)E * 2 * DD * 2);    // 256 MB
  u16* suE    = (u16*)alloc((size_t)E * DD * 2);        // 128 MB
  int  maxME  = (ELG > E) ? ELG : E;
  u16* egpB   = (u16*)alloc((size_t)maxME * DD * 2);    // 128 MB
  u16* sgN    = (u16*)alloc((size_t)N * DD * 2);
  u16* dgduN  = (u16*)alloc((size_t)N * 2 * DD * 2);
  u16* suN    = (u16*)alloc((size_t)N * DD * 2);
  int* cnt_e  = (int*)alloc((size_t)E * 4);
  int* rptr_e = (int*)alloc((size_t)(E + 1) * 4);
  int* head_e = (int*)alloc((size_t)E * 4);
  int* srcs_e = (int*)alloc((size_t)ELG * 4);
  int* pos_e  = (int*)alloc((size_t)ELG * 4);
  int* cnt_n  = (int*)alloc((size_t)N * 4);
  int* rptr_n = (int*)alloc((size_t)(N + 1) * 4);
  int* head_n = (int*)alloc((size_t)N * 4);
  int* srcs_n = (int*)alloc((size_t)E * 4);
  int* pos_n  = (int*)alloc((size_t)E * 4);
  int* bsum   = (int*)alloc(512 * 4);
  if (ws_size < off) return;  // visible failure if ws too small (base layout)

  // Fused layer-2 egp needs its OWN buffer (egpB is still being read for
  // layer-1 by concurrent gfin blocks -> cross-block race if reused).
  // Allocate if ws allows; else fall back to the R10 proj_single path.
  size_t off_base = off;
  u16* egp2 = (u16*)alloc((size_t)E * DD * 2);          // +128 MB
  bool fuse = (ws_size >= off);
  if (!fuse) { off = off_base; egp2 = nullptr; }

  float* xn_out = (float*)d_out;
  float* ea_out = (float*)d_out + (size_t)N * DD;

  // --- prep: weights + folded biases ---
  // wt slots 0..9 = eu{sg,dg,eg,du,su}, nu{sg,dg,eg,du,su}
  prep_weights<<<10, 256, 0, stream>>>(
      (const float*)d_in[5], (const float*)d_in[7], (const float*)d_in[9],
      (const float*)d_in[13], (const float*)d_in[11],
      (const float*)d_in[17], (const float*)d_in[19], (const float*)d_in[21],
      (const float*)d_in[25], (const float*)d_in[23], wt);
  fold_bias<<<1, 128, 0, stream>>>(
      (const float*)d_in[6], (const float*)d_in[8], (const float*)d_in[10],
      (const float*)d_in[14], (const float*)d_in[12],
      (const float*)d_in[18], (const float*)d_in[20], (const float*)d_in[22],
      (const float*)d_in[26], (const float*)d_in[24], biasF);

  // --- CSR builds: counts -> rowptr -> (src, pos) counting-sort ---
  hipMemsetAsync(cnt_e, 0, (size_t)E * 4, stream);
  hipMemsetAsync(cnt_n, 0, (size_t)N * 4, stream);
  hist_kernel<<<(ELG + 255) / 256, 256, 0, stream>>>(lgei + ELG, ELG, cnt_e);
  hist_kernel<<<(E + 255) / 256, 256, 0, stream>>>(gei + E, E, cnt_n);

  int NBe = (E + 1023) / 1024;
  scan1_kernel<<<NBe, 256, 0, stream>>>(cnt_e, E, rptr_e, bsum);
  scan2_kernel<<<1, 256, 0, stream>>>(bsum, NBe);
  scan3_kernel<<<(E + 255) / 256, 256, 0, stream>>>(rptr_e, bsum, E, ELG, head_e);
  eid_kernel<<<(ELG + 255) / 256, 256, 0, stream>>>(lgei, lgei + ELG, ELG, head_e,
                                                    srcs_e, pos_e);

  int NBn = (N + 1023) / 1024;
  scan1_kernel<<<NBn, 256, 0, stream>>>(cnt_n, N, rptr_n, bsum);
  scan2_kernel<<<1, 256, 0, stream>>>(bsum, NBn);
  scan3_kernel<<<(N + 255) / 256, 256, 0, stream>>>(rptr_n, bsum, N, E, head_n);
  eid_kernel<<<(E + 255) / 256, 256, 0, stream>>>(gei, gei + E, E, head_n,
                                                  srcs_n, pos_n);

  int gE = (E + 127) / 128, gLG = (ELG + 127) / 128, gN = (N + 127) / 128;

  // --- mega: all 3 input-only projections in one launch ---
  proj_mega<<<gE + gLG + gN, 256, 0, stream>>>(
      gE, gLG,
      E, ex, wt, biasF, sgE, dgduE, suE,
      ELG, lga, wt + 2 * 16384, pos_e, egpB,
      N, x, wt + 5 * 16384, biasF + 384, sgN, dgduN, suN);

  if (fuse) {
    // --- Layer 1 finalize + fused layer-2 egp projection ---
    gfin_kernel<true><<<(E + 15) / 16, 256, 0, stream>>>(
        E, rptr_e, srcs_e, sgE, dgduE, suE, egpB,
        (const float*)d_in[15], (const float*)d_in[16], ex, ea_out,
        wt + 7 * 16384, pos_n, egp2);
    gfin_kernel<false><<<(N + 15) / 16, 256, 0, stream>>>(
        N, rptr_n, srcs_n, sgN, dgduN, suN, egp2,
        (const float*)d_in[27], (const float*)d_in[28], x, xn_out,
        nullptr, nullptr, nullptr);
  } else {
    // --- fallback: R10 path ---
    gfin_kernel<false><<<(E + 15) / 16, 256, 0, stream>>>(
        E, rptr_e, srcs_e, sgE, dgduE, suE, egpB,
        (const float*)d_in[15], (const float*)d_in[16], ex, ea_out,
        nullptr, nullptr, nullptr);
    proj_single<<<gE, 256, 0, stream>>>(
        E, ea_out, wt + 7 * 16384, pos_n, egpB);
    gfin_kernel<false><<<(N + 15) / 16, 256, 0, stream>>>(
        N, rptr_n, srcs_n, sgN, dgduN, suN, egpB,
        (const float*)d_in[27], (const float*)d_in[28], x, xn_out,
        nullptr, nullptr, nullptr);
  }
}

// Round 12
// 808.612 us; speedup vs baseline: 1.0738x; 1.0738x over previous
//
#include <hip/hip_runtime.h>
#include <stdint.h>

#define DD 128
#define WPAD 72  // wave C-buffer row stride (u16): 144B rotates banks across
                 // rows and keeps 16B alignment for u16x8 reads.

typedef __bf16 bf16x8 __attribute__((ext_vector_type(8)));
typedef float f32x4 __attribute__((ext_vector_type(4)));
typedef unsigned short u16;
typedef u16 u16x8 __attribute__((ext_vector_type(8)));

// Plain cast -> single HW cvt instruction (RNE), vs ~5 VALU ops manual.
__device__ __forceinline__ u16 f2bf(float f) {
  union { __bf16 h; u16 u; } v; v.h = (__bf16)f; return v.u;
}
__device__ __forceinline__ float bf2f(u16 b) {
  union { uint32_t u; float f; } v; v.u = (uint32_t)b << 16; return v.f;
}
__device__ __forceinline__ float silu_f(float x) {
  return x / (1.0f + __expf(-x));
}
__device__ __forceinline__ uint32_t pkbf(float lo, float hi) {
  return (uint32_t)f2bf(lo) | ((uint32_t)f2bf(hi) << 16);
}

// ---- f32 A staging (streamed): issue to regs / bf16-convert into LDS ----
// LDS layout: Ab[row*128 + ((cc ^ (row&7))<<3) + (k&7)]  (cc = k>>3).
// PLAIN loads (nt loads broke gfin's resid L3 hits -- R4/R5 evidence).
struct ARegs { f32x4 v[8][2]; };

__device__ __forceinline__ void issue_A(ARegs& r, const float* __restrict__ src,
                                        int base, int M, int tid) {
#pragma unroll
  for (int i = 0; i < 8; ++i) {
    int id = tid + (i << 8);
    int row = id >> 4;
    int cc = id & 15;
    if (base + row < M) {
      const f32x4* p = (const f32x4*)(src + (size_t)(base + row) * DD + cc * 8);
      r.v[i][0] = p[0];
      r.v[i][1] = p[1];
    } else {
      r.v[i][0] = (f32x4){0.f, 0.f, 0.f, 0.f};
      r.v[i][1] = (f32x4){0.f, 0.f, 0.f, 0.f};
    }
  }
}

__device__ __forceinline__ void write_A(u16* Ab, const ARegs& r, int tid) {
#pragma unroll
  for (int i = 0; i < 8; ++i) {
    int id = tid + (i << 8);
    int row = id >> 4;
    int cc = id & 15;
    u16x8 o;
    o[0] = f2bf(r.v[i][0][0]); o[1] = f2bf(r.v[i][0][1]);
    o[2] = f2bf(r.v[i][0][2]); o[3] = f2bf(r.v[i][0][3]);
    o[4] = f2bf(r.v[i][1][0]); o[5] = f2bf(r.v[i][1][1]);
    o[6] = f2bf(r.v[i][1][2]); o[7] = f2bf(r.v[i][1][3]);
    *(u16x8*)&Ab[row * DD + ((cc ^ (row & 7)) << 3)] = o;
  }
}

// ---- B fragments preloaded to registers. Issue B loads BEFORE the store
// burst: vmcnt FIFO means waiting for B leaves stores outstanding
// (R4/R5: effective BW 1.88 -> 2.5 TB/s).
struct BRegs { bf16x8 b[4][4]; };  // [kk][n]

__device__ __forceinline__ void load_B(BRegs& br, const u16* __restrict__ wt,
                                       int lane, int wc) {
  int g = lane >> 4, r15 = lane & 15;
  const u16* wbase = wt + (size_t)(wc * 64 + r15) * DD;
#pragma unroll
  for (int kk = 0; kk < 4; ++kk) {
    int ko = ((kk << 2) | g) << 3;
#pragma unroll
    for (int n = 0; n < 4; ++n)
      br.b[kk][n] = *(const bf16x8*)&wbase[n * 16 * DD + ko];
  }
}

// ---- MFMA stage from LDS A + register B. Same lane->k bijection on A and B
// so any hw k-permutation cancels. Each wave reads only its own 64 A-rows.
__device__ __forceinline__ void mma_stage(const u16* Ab, const BRegs& br,
                                          f32x4 acc[4][4], int lane, int wr) {
  int g = lane >> 4, r15 = lane & 15, s = r15 & 7;
#pragma unroll
  for (int kk = 0; kk < 4; ++kk) {
    bf16x8 af[4];
#pragma unroll
    for (int m = 0; m < 4; ++m) {
      int rr = wr * 64 + m * 16 + r15;
      af[m] = *(const bf16x8*)&Ab[rr * DD + ((((kk << 2) | g) ^ s) << 3)];
    }
#pragma unroll
    for (int m = 0; m < 4; ++m)
#pragma unroll
      for (int n = 0; n < 4; ++n)
        acc[m][n] = __builtin_amdgcn_mfma_f32_16x16x32_bf16(af[m], br.b[kk][n], acc[m][n], 0, 0, 0);
  }
}

// acc init with per-column bias folded in (C-in of first MFMA).
__device__ __forceinline__ void init_acc(f32x4 a[4][4], const float* __restrict__ bias,
                                         int lane, int wc) {
  int l15 = lane & 15;
#pragma unroll
  for (int n = 0; n < 4; ++n) {
    float b = bias ? bias[wc * 64 + n * 16 + l15] : 0.f;
    f32x4 v = {b, b, b, b};
#pragma unroll
    for (int m = 0; m < 4; ++m) a[m][n] = v;
  }
}

// C/D: col=lane&15, row=(lane>>4)*4+reg. shfl-pair -> u32 per 2 cols, into
// this WAVE'S PRIVATE [32][WPAD] u16 staging buffer -- HALF the 64-row wave
// tile per pass (half = 0: m 0,1; half = 1: m 2,3). Halved buffer drops block
// LDS 70 -> 52 KB => 3 blocks/CU instead of 2 (more out-of-phase memory
// streams per CU). Same-wave write->read->overwrite is ordered by the LDS
// pipeline; no barrier needed (R9).
__device__ __forceinline__ void store_lds_half(const f32x4 acc[4][4], u16* wb,
                                               int lane, int half) {
  int l15 = lane & 15;
  bool oddl = lane & 1;
#pragma unroll
  for (int mm = 0; mm < 2; ++mm) {
    int m = half * 2 + mm;
    int rb = mm * 16 + ((lane >> 4) << 2);
#pragma unroll
    for (int j = 0; j < 4; ++j) {
      int row = rb + j;  // 0..31 within the half-buffer
#pragma unroll
      for (int n0 = 0; n0 < 4; n0 += 2) {
        int c0 = n0 * 16 + l15;
        float v0 = acc[m][n0][j];
        float v1 = acc[m][n0 + 1][j];
        float t0 = __shfl_xor(v0, 1);
        float t1 = __shfl_xor(v1, 1);
        uint32_t pk = oddl ? pkbf(t1, v1) : pkbf(v0, t0);
        int col2 = oddl ? (c0 + 15) : c0;
        *(uint32_t*)&wb[row * WPAD + col2] = pk;
      }
    }
  }
}

// Copy-out: half-buffer -> global, u16x8 (16B) per lane; 8 lanes cover one
// 128B row-segment (this wave's col-half), 8 rows per pass, 4 passes.
// (R8: 16B/lane coalesced stores were the 330->271us win.)
__device__ __forceinline__ void copy_out_half(const u16* wb, u16* __restrict__ out,
                                              size_t rs, int co, int base, int M,
                                              int lane, int wr, int wc, int half,
                                              const int* sPerm) {
  int lr8 = lane >> 3;
  int lc = (lane & 7) * 8;
#pragma unroll
  for (int p = 0; p < 4; ++p) {
    int lrow = p * 8 + lr8;  // 0..31
    int row = wr * 64 + half * 32 + lrow;
    if (base + row < M) {
      int orow = sPerm ? sPerm[row] : (base + row);
      u16x8 v = *(const u16x8*)&wb[lrow * WPAD + lc];
      *(u16x8*)&out[(size_t)orow * rs + co + wc * 64 + lc] = v;
    }
  }
}

__device__ __forceinline__ void store_stage(const f32x4 acc[4][4], u16* wb,
                                            u16* __restrict__ out, size_t rs, int co,
                                            int base, int M, int lane, int wr, int wc,
                                            const int* sPerm) {
  store_lds_half(acc, wb, lane, 0);
  copy_out_half(wb, out, rs, co, base, M, lane, wr, wc, 0, sPerm);
  store_lds_half(acc, wb, lane, 1);
  copy_out_half(wb, out, rs, co, base, M, lane, wr, wc, 1, sPerm);
}

// ---- proj bodies (one 128-row tile per block, 64x64 wave tile) ----
__device__ __forceinline__ void proj_four_body(
    int M, int base, const float* __restrict__ src, const u16* __restrict__ wt,
    const float* __restrict__ bF, u16* __restrict__ o_sg,
    u16* __restrict__ o_dgdu, u16* __restrict__ o_su, u16* Ab, u16* Wb) {
  int tid = threadIdx.x, lane = tid & 63, wid = tid >> 6;
  int wr = wid >> 1, wc = wid & 1;
  BRegs b0, b1;
  {
    ARegs ar;
    issue_A(ar, src, base, M, tid);        // HBM loads first (longest pole)
    load_B(b0, wt + 0 * 16384, lane, wc);  // L2 loads behind them
    write_A(Ab, ar, tid);                  // waits A only (B newer in FIFO)
  }
  __syncthreads();  // the ONLY block barrier
  u16* wb = Wb + wid * (32 * WPAD);
  f32x4 acc[4][4];
  init_acc(acc, bF, lane, wc);
  mma_stage(Ab, b0, acc, lane, wr);                        // sg
  load_B(b1, wt + 1 * 16384, lane, wc);  // next B before store traffic
  store_stage(acc, wb, o_sg, DD, 0, base, M, lane, wr, wc, nullptr);
  init_acc(acc, nullptr, lane, wc);
  mma_stage(Ab, b1, acc, lane, wr);                        // dg (bias in sg)
  load_B(b0, wt + 3 * 16384, lane, wc);
  store_stage(acc, wb, o_dgdu, 2 * DD, 0, base, M, lane, wr, wc, nullptr);
  init_acc(acc, bF + 128, lane, wc);
  mma_stage(Ab, b0, acc, lane, wr);                        // du + bdu
  load_B(b1, wt + 4 * 16384, lane, wc);
  store_stage(acc, wb, o_dgdu, 2 * DD, DD, base, M, lane, wr, wc, nullptr);
  init_acc(acc, bF + 256, lane, wc);
  mma_stage(Ab, b1, acc, lane, wr);                        // su + bsu
  store_stage(acc, wb, o_su, DD, 0, base, M, lane, wr, wc, nullptr);
}

__device__ __forceinline__ void proj_one_body(
    int M, int base, const float* __restrict__ src, const u16* __restrict__ wt,
    const int* __restrict__ perm, u16* __restrict__ o,
    u16* Ab, u16* Wb, int* sPerm) {
  int tid = threadIdx.x, lane = tid & 63, wid = tid >> 6;
  int wr = wid >> 1, wc = wid & 1;
  BRegs b0;
  {
    ARegs ar;
    issue_A(ar, src, base, M, tid);
    if (perm && tid < 128)
      sPerm[tid] = (base + tid < M) ? perm[base + tid] : 0;
    load_B(b0, wt, lane, wc);
    write_A(Ab, ar, tid);
  }
  __syncthreads();
  u16* wb = Wb + wid * (32 * WPAD);
  f32x4 acc[4][4];
  init_acc(acc, nullptr, lane, wc);
  mma_stage(Ab, b0, acc, lane, wr);
  store_stage(acc, wb, o, DD, 0, base, M, lane, wr, wc, perm ? sPerm : nullptr);
}

// ========== mega-launch: the 3 dependency-free projections in ONE grid =====
// (R10: 833->809us; types in contiguous grid ranges keep the tight L3 window.)
__global__ void __launch_bounds__(256, 2) proj_mega(
    int gE, int gLG,
    int E, const float* __restrict__ ex, const u16* __restrict__ wtE,
    const float* __restrict__ bFE,
    u16* __restrict__ sgE, u16* __restrict__ dgduE, u16* __restrict__ suE,
    int ELG, const float* __restrict__ lga, const u16* __restrict__ wtLG,
    const int* __restrict__ permE, u16* __restrict__ egp,
    int N, const float* __restrict__ x, const u16* __restrict__ wtN,
    const float* __restrict__ bFN,
    u16* __restrict__ sgN, u16* __restrict__ dgduN, u16* __restrict__ suN) {
  __shared__ u16 Ab[128 * DD];          // 32 KB  A tile
  __shared__ u16 Wb[4 * 32 * WPAD];     // 4 x 4.5 KB wave-private C staging
  __shared__ int sPerm[128];
  int b = blockIdx.x;
  if (b < gE)
    proj_four_body(E, b * 128, ex, wtE, bFE, sgE, dgduE, suE, Ab, Wb);
  else if (b < gE + gLG)
    proj_one_body(ELG, (b - gE) * 128, lga, wtLG, permE, egp, Ab, Wb, sPerm);
  else
    proj_four_body(N, (b - gE - gLG) * 128, x, wtN, bFN, sgN, dgduN, suN, Ab, Wb);
}

// Standalone single-stage projection (layer-2 egp: depends on ea_out).
__global__ void __launch_bounds__(256, 2) proj_single(
    int M, const float* __restrict__ src, const u16* __restrict__ wt,
    const int* __restrict__ perm, u16* __restrict__ o) {
  __shared__ u16 Ab[128 * DD];
  __shared__ u16 Wb[4 * 32 * WPAD];
  __shared__ int sPerm[128];
  proj_one_body(M, blockIdx.x * 128, src, wt, perm, o, Ab, Wb, sPerm);
}

// ================= CSR build =================
__global__ void __launch_bounds__(256) hist_kernel(const int* __restrict__ dst,
                                                   int Me, int* __restrict__ cnt) {
  int i = blockIdx.x * blockDim.x + threadIdx.x;
  if (i < Me) atomicAdd(&cnt[dst[i]], 1);
}

__global__ void __launch_bounds__(256) scan1_kernel(const int* __restrict__ cnt, int M,
                                                    int* __restrict__ out,
                                                    int* __restrict__ bsum) {
  __shared__ int sh[256];
  int t = threadIdx.x;
  int i0 = blockIdx.x * 1024 + t * 4;
  int v[4];
#pragma unroll
  for (int k = 0; k < 4; ++k) v[k] = (i0 + k < M) ? cnt[i0 + k] : 0;
  int s = v[0] + v[1] + v[2] + v[3];
  sh[t] = s;
  __syncthreads();
#pragma unroll
  for (int off = 1; off < 256; off <<= 1) {
    int x = (t >= off) ? sh[t - off] : 0;
    __syncthreads();
    sh[t] += x;
    __syncthreads();
  }
  int run = sh[t] - s;  // exclusive
  if (t == 255) bsum[blockIdx.x] = sh[255];
#pragma unroll
  for (int k = 0; k < 4; ++k) {
    if (i0 + k < M) out[i0 + k] = run;
    run += v[k];
  }
}

__global__ void __launch_bounds__(256) scan2_kernel(int* __restrict__ bsum, int NB) {
  __shared__ int sh[512];
  int t = threadIdx.x;
  for (int i = t; i < 512; i += 256) sh[i] = (i < NB) ? bsum[i] : 0;
  __syncthreads();
  for (int off = 1; off < 512; off <<= 1) {
    int tmp[2];
#pragma unroll
    for (int q = 0; q < 2; ++q) {
      int i = t + q * 256;
      tmp[q] = (i >= off) ? sh[i - off] : 0;
    }
    __syncthreads();
#pragma unroll
    for (int q = 0; q < 2; ++q) sh[t + q * 256] += tmp[q];
    __syncthreads();
  }
  for (int i = t; i < NB; i += 256) bsum[i] = (i == 0) ? 0 : sh[i - 1];
}

__global__ void __launch_bounds__(256) scan3_kernel(int* __restrict__ rowptr,
                                                    const int* __restrict__ bscan,
                                                    int M, int Medges,
                                                    int* __restrict__ head) {
  int i = blockIdx.x * blockDim.x + threadIdx.x;
  if (i < M) {
    int v = rowptr[i] + bscan[i >> 10];
    rowptr[i] = v;
    head[i] = v;
  }
  if (i == 0) rowptr[M] = Medges;
}

// Counting-sort: slot s gets the edge's src; pos[e] = s records the inverse
// permutation so proj can write egp directly in gather order.
__global__ void __launch_bounds__(256) eid_kernel(const int* __restrict__ src,
                                                  const int* __restrict__ dst, int Me,
                                                  int* __restrict__ head,
                                                  int* __restrict__ srcs,
                                                  int* __restrict__ pos) {
  int i = blockIdx.x * blockDim.x + threadIdx.x;
  if (i < Me) {
    int s = atomicAdd(&head[dst[i]], 1);
    srcs[s] = src[i];
    pos[i] = s;
  }
}

// ================= misc prep =================
// W (k-major [128][128] f32) -> wt[n*128+k] bf16.
__global__ void prep_weights(const float* __restrict__ w0, const float* __restrict__ w1,
                             const float* __restrict__ w2, const float* __restrict__ w3,
                             const float* __restrict__ w4, const float* __restrict__ w5,
                             const float* __restrict__ w6, const float* __restrict__ w7,
                             const float* __restrict__ w8, const float* __restrict__ w9,
                             u16* __restrict__ wt) {
  const float* W;
  switch (blockIdx.x) {
    case 0: W = w0; break; case 1: W = w1; break; case 2: W = w2; break;
    case 3: W = w3; break; case 4: W = w4; break; case 5: W = w5; break;
    case 6: W = w6; break; case 7: W = w7; break; case 8: W = w8; break;
    default: W = w9; break;
  }
  u16* dst = wt + blockIdx.x * 16384;
  for (int o = threadIdx.x; o < 16384; o += 256) {
    int n = o >> 7, k = o & 127;
    dst[o] = f2bf(W[k * DD + n]);
  }
}

// Folded bias table: [0..2]*128 = eu {sg+dg+eg, du, su}; [3..5]*128 = nu same.
__global__ void fold_bias(const float* __restrict__ e_sg, const float* __restrict__ e_dg,
                          const float* __restrict__ e_eg, const float* __restrict__ e_du,
                          const float* __restrict__ e_su,
                          const float* __restrict__ n_sg, const float* __restrict__ n_dg,
                          const float* __restrict__ n_eg, const float* __restrict__ n_du,
                          const float* __restrict__ n_su, float* __restrict__ out) {
  int i = threadIdx.x;
  if (i < 128) {
    out[i]        = e_sg[i] + e_dg[i] + e_eg[i];
    out[128 + i]  = e_du[i];
    out[256 + i]  = e_su[i];
    out[384 + i]  = n_sg[i] + n_dg[i] + n_eg[i];
    out[512 + i]  = n_du[i];
    out[640 + i]  = n_su[i];
  }
}

// ============ gather-finalize: 16 lanes/row, 8 cols/lane, 4 rows/wave ========
// per row r: for s in [rptr[r],rptr[r+1]):
//   sv=srcs[s]
//   gate = silu(sg'[r] + dg[sv] + egp[s]); ax += gate * du'[sv]
// egp is pre-permuted (written at pos[e]) -> sequential reads here.
// vx = su'[r] + ax; LN; silu; + resid(f32); write f32 out.
// Kept LEAN on purpose: R11's fused MFMA epilogue cost more than it saved
// (occupancy + barrier + 4B scatters); gather kernels need max TLP (R7).
__global__ void __launch_bounds__(256) gfin_kernel(
    int M, const int* __restrict__ rptr,
    const int* __restrict__ srcs,
    const u16* __restrict__ sg_t, const u16* __restrict__ dgdu_t,
    const u16* __restrict__ su_t, const u16* __restrict__ egp,
    const float* __restrict__ gamma, const float* __restrict__ beta,
    const float* __restrict__ resid, float* __restrict__ out) {
  int gtid = blockIdx.x * blockDim.x + threadIdx.x;
  int r = gtid >> 4;
  int l16 = gtid & 15;
  if (r >= M) return;
  int c = l16 * 8;

  u16x8 sgp = *(const u16x8*)&sg_t[(size_t)r * DD + c];
  float sg[8], ax[8];
#pragma unroll
  for (int k = 0; k < 8; ++k) { sg[k] = bf2f(sgp[k]); ax[k] = 0.f; }

  int segb = rptr[r], sege = rptr[r + 1];
  for (int s = segb; s < sege; ++s) {
    int sv = srcs[s];
    u16x8 gp = *(const u16x8*)&egp[(size_t)s * DD + c];
    u16x8 dgp = *(const u16x8*)&dgdu_t[(size_t)sv * (2 * DD) + c];
    u16x8 dup = *(const u16x8*)&dgdu_t[(size_t)sv * (2 * DD) + DD + c];
#pragma unroll
    for (int k = 0; k < 8; ++k) {
      float g = silu_f(sg[k] + bf2f(dgp[k]) + bf2f(gp[k]));
      ax[k] += g * bf2f(dup[k]);
    }
  }

  u16x8 sup = *(const u16x8*)&su_t[(size_t)r * DD + c];
  float v[8];
  float sum = 0.f;
#pragma unroll
  for (int k = 0; k < 8; ++k) { v[k] = bf2f(sup[k]) + ax[k]; sum += v[k]; }
#pragma unroll
  for (int off = 1; off <= 8; off <<= 1) sum += __shfl_xor(sum, off);
  float mean = sum * (1.0f / 128.0f);
  float sq = 0.f;
#pragma unroll
  for (int k = 0; k < 8; ++k) { v[k] -= mean; sq += v[k] * v[k]; }
#pragma unroll
  for (int off = 1; off <= 8; off <<= 1) sq += __shfl_xor(sq, off);
  float rs = rsqrtf(sq * (1.0f / 128.0f) + 1e-5f);

  float4 gm0 = *(const float4*)&gamma[c];
  float4 gm1 = *(const float4*)&gamma[c + 4];
  float4 bt0 = *(const float4*)&beta[c];
  float4 bt1 = *(const float4*)&beta[c + 4];
  float4 rr0 = *(const float4*)&resid[(size_t)r * DD + c];
  float4 rr1 = *(const float4*)&resid[(size_t)r * DD + c + 4];
  float gmv[8] = {gm0.x, gm0.y, gm0.z, gm0.w, gm1.x, gm1.y, gm1.z, gm1.w};
  float btv[8] = {bt0.x, bt0.y, bt0.z, bt0.w, bt1.x, bt1.y, bt1.z, bt1.w};
  float rrv[8] = {rr0.x, rr0.y, rr0.z, rr0.w, rr1.x, rr1.y, rr1.z, rr1.w};
  float o[8];
#pragma unroll
  for (int k = 0; k < 8; ++k)
    o[k] = silu_f(v[k] * rs * gmv[k] + btv[k]) + rrv[k];
  float4 o0 = {o[0], o[1], o[2], o[3]};
  float4 o1 = {o[4], o[5], o[6], o[7]};
  *(float4*)&out[(size_t)r * DD + c] = o0;
  *(float4*)&out[(size_t)r * DD + c + 4] = o1;
}

extern "C" void kernel_launch(void* const* d_in, const int* in_sizes, int n_in,
                              void* d_out, int out_size, void* d_ws, size_t ws_size,
                              hipStream_t stream) {
  const float* x   = (const float*)d_in[0];
  const float* ex  = (const float*)d_in[1];
  const float* lga = (const float*)d_in[2];
  const int* gei   = (const int*)d_in[3];
  const int* lgei  = (const int*)d_in[4];
  int N   = in_sizes[0] / DD;
  int E   = in_sizes[3] / 2;
  int ELG = in_sizes[4] / 2;

  char* p = (char*)d_ws;
  size_t off = 0;
  auto alloc = [&](size_t bytes) { char* q = p + off; off += (bytes + 255) & ~255ull; return q; };

  u16* wt     = (u16*)alloc((size_t)10 * 16384 * 2);
  float* biasF = (float*)alloc(768 * 4);
  u16* sgE    = (u16*)alloc((size_t)E * DD * 2);        // 128 MB
  u16* dgduE  = (u16*)alloc((size_t)E * 2 * DD * 2);    // 256 MB
  u16* suE    = (u16*)alloc((size_t)E * DD * 2);        // 128 MB
  int  maxME  = (ELG > E) ? ELG : E;
  u16* egpB   = (u16*)alloc((size_t)maxME * DD * 2);    // 128 MB
  u16* sgN    = (u16*)alloc((size_t)N * DD * 2);
  u16* dgduN  = (u16*)alloc((size_t)N * 2 * DD * 2);
  u16* suN    = (u16*)alloc((size_t)N * DD * 2);
  int* cnt_e  = (int*)alloc((size_t)E * 4);
  int* rptr_e = (int*)alloc((size_t)(E + 1) * 4);
  int* head_e = (int*)alloc((size_t)E * 4);
  int* srcs_e = (int*)alloc((size_t)ELG * 4);
  int* pos_e  = (int*)alloc((size_t)ELG * 4);
  int* cnt_n  = (int*)alloc((size_t)N * 4);
  int* rptr_n = (int*)alloc((size_t)(N + 1) * 4);
  int* head_n = (int*)alloc((size_t)N * 4);
  int* srcs_n = (int*)alloc((size_t)E * 4);
  int* pos_n  = (int*)alloc((size_t)E * 4);
  int* bsum   = (int*)alloc(512 * 4);
  if (ws_size < off) return;  // visible failure if ws too small

  float* xn_out = (float*)d_out;
  float* ea_out = (float*)d_out + (size_t)N * DD;

  // --- prep: weights + folded biases ---
  // wt slots 0..9 = eu{sg,dg,eg,du,su}, nu{sg,dg,eg,du,su}
  prep_weights<<<10, 256, 0, stream>>>(
      (const float*)d_in[5], (const float*)d_in[7], (const float*)d_in[9],
      (const float*)d_in[13], (const float*)d_in[11],
      (const float*)d_in[17], (const float*)d_in[19], (const float*)d_in[21],
      (const float*)d_in[25], (const float*)d_in[23], wt);
  fold_bias<<<1, 128, 0, stream>>>(
      (const float*)d_in[6], (const float*)d_in[8], (const float*)d_in[10],
      (const float*)d_in[14], (const float*)d_in[12],
      (const float*)d_in[18], (const float*)d_in[20], (const float*)d_in[22],
      (const float*)d_in[26], (const float*)d_in[24], biasF);

  // --- CSR builds: counts -> rowptr -> (src, pos) counting-sort ---
  hipMemsetAsync(cnt_e, 0, (size_t)E * 4, stream);
  hipMemsetAsync(cnt_n, 0, (size_t)N * 4, stream);
  hist_kernel<<<(ELG + 255) / 256, 256, 0, stream>>>(lgei + ELG, ELG, cnt_e);
  hist_kernel<<<(E + 255) / 256, 256, 0, stream>>>(gei + E, E, cnt_n);

  int NBe = (E + 1023) / 1024;
  scan1_kernel<<<NBe, 256, 0, stream>>>(cnt_e, E, rptr_e, bsum);
  scan2_kernel<<<1, 256, 0, stream>>>(bsum, NBe);
  scan3_kernel<<<(E + 255) / 256, 256, 0, stream>>>(rptr_e, bsum, E, ELG, head_e);
  eid_kernel<<<(ELG + 255) / 256, 256, 0, stream>>>(lgei, lgei + ELG, ELG, head_e,
                                                    srcs_e, pos_e);

  int NBn = (N + 1023) / 1024;
  scan1_kernel<<<NBn, 256, 0, stream>>>(cnt_n, N, rptr_n, bsum);
  scan2_kernel<<<1, 256, 0, stream>>>(bsum, NBn);
  scan3_kernel<<<(E + 255) / 256, 256, 0, stream>>>(rptr_n, bsum, N, E, head_n);
  eid_kernel<<<(E + 255) / 256, 256, 0, stream>>>(gei, gei + E, E, head_n,
                                                  srcs_n, pos_n);

  int gE = (E + 127) / 128, gLG = (ELG + 127) / 128, gN = (N + 127) / 128;

  // --- mega: all 3 input-only projections in one launch ---
  proj_mega<<<gE + gLG + gN, 256, 0, stream>>>(
      gE, gLG,
      E, ex, wt, biasF, sgE, dgduE, suE,
      ELG, lga, wt + 2 * 16384, pos_e, egpB,
      N, x, wt + 5 * 16384, biasF + 384, sgN, dgduN, suN);

  // --- Layer 1 finalize ---
  gfin_kernel<<<(E + 15) / 16, 256, 0, stream>>>(
      E, rptr_e, srcs_e, sgE, dgduE, suE, egpB,
      (const float*)d_in[15], (const float*)d_in[16], ex, ea_out);

  // --- Layer 2: egp from ea, then finalize ---
  proj_single<<<gE, 256, 0, stream>>>(
      E, ea_out, wt + 7 * 16384, pos_n, egpB);
  gfin_kernel<<<(N + 15) / 16, 256, 0, stream>>>(
      N, rptr_n, srcs_n, sgN, dgduN, suN, egpB,
      (const float*)d_in[27], (const float*)d_in[28], x, xn_out);
}